// Round 3
// baseline (113.040 us; speedup 1.0000x reference)
//
#include <hip/hip_runtime.h>

#define RATE 0.001f

typedef float f2 __attribute__((ext_vector_type(2)));
typedef float f4 __attribute__((ext_vector_type(4)));

static __device__ __forceinline__ f2 splat2(float v) { f2 r; r.x = v; r.y = v; return r; }

// ---------------- Kernel A: vj[b,o] = relu(dot(a_b, w_o) + bias_o), plus S_b = rowsum(a_b).
// Blocks [0, nOb): 4 waves, wave handles one o (all 8 batch rows, full I).
// Blocks [nOb, nOb+2): wave w sums activation row (blk-nOb)*4 + w.
template<int I>
__global__ __launch_bounds__(256) void hebb_vj(
    const float* __restrict__ vi,    // (8, I)
    const float* __restrict__ w,     // (O, I)
    const float* __restrict__ bias,  // (O,)
    float* __restrict__ vj_out,      // (8, O)
    float* __restrict__ S_out,       // (8,)
    int O, int nOb)
{
    const int tid  = threadIdx.x;
    const int lane = tid & 63;
    const int wid  = tid >> 6;
    constexpr int ITERS = I / 256;   // 64 lanes * 4 floats per iter (per wave)

    if ((int)blockIdx.x >= nOb) {
        // ---- rowsum blocks ----
        const int row = ((int)blockIdx.x - nOb) * 4 + wid;
        const float* __restrict__ a = vi + (size_t)row * I;
        float s = 0.f;
        for (int it = 0; it < ITERS; ++it) {
            const f4 v = *(const f4*)(a + it * 256 + lane * 4);
            s += (v.x + v.y) + (v.z + v.w);
        }
#pragma unroll
        for (int off = 1; off < 64; off <<= 1) s += __shfl_xor(s, off, 64);
        if (lane == 0) S_out[row] = s;
        return;
    }

    const int o = (int)blockIdx.x * 4 + wid;
    const float* __restrict__ wrow = w + (size_t)o * I;
    const float bo = bias[o];

    float dot[8];
#pragma unroll
    for (int b = 0; b < 8; ++b) dot[b] = 0.f;

    for (int it = 0; it < ITERS; ++it) {
        const int base = it * 256 + lane * 4;
        const f4 wv = *(const f4*)(wrow + base);
#pragma unroll
        for (int b = 0; b < 8; ++b) {
            const f4 a = *(const f4*)(vi + (size_t)b * I + base);
#pragma unroll
            for (int e = 0; e < 4; ++e) dot[b] = fmaf(a[e], wv[e], dot[b]);
        }
    }
#pragma unroll
    for (int b = 0; b < 8; ++b) {
#pragma unroll
        for (int off = 1; off < 64; off <<= 1) dot[b] += __shfl_xor(dot[b], off, 64);
    }
    if (lane == 0) {
#pragma unroll
        for (int b = 0; b < 8; ++b) vj_out[(size_t)b * O + o] = fmaxf(dot[b] + bo, 0.f);
    }
}

// ---------------- Kernel B: the meta-MLP accumulation (single streaming pass).
// out[b,o] = vj + scale*( sum_i a_i*(sum_h relu(a_i*p_h + w_oi*q_h + vj*r_h + c1b_h)*c2w_h)
//                          + c2b*S_b )
// One block per o; activations staged in LDS (32 KB chunks of 8x1024); w-row streamed
// from global (unique per block -> no L2 hotspot). Wave w owns batch rows {2w, 2w+1}.
template<int I>
__global__ __launch_bounds__(256, 4) void hebb_main(
    const float* __restrict__ vi,    // (8, I) activations
    const float* __restrict__ w,     // (O, I)
    const float* __restrict__ vjA,   // (8, O) precomputed vj
    const float* __restrict__ S,     // (8,)
    const float* __restrict__ c1w,   // (8, 3): p,q,r
    const float* __restrict__ c1b,   // (8,)
    const float* __restrict__ c2w,   // (8,)
    const float* __restrict__ c2b_p, // scalar
    const int*   __restrict__ bn_p,  // scalar batch_num
    float* __restrict__ out,         // (8, O)
    int O)
{
    __shared__ float sA[8 * 1024];   // 32 KB: 8 rows x 1024-col chunk

    const int o    = blockIdx.x;
    const int tid  = threadIdx.x;
    const int lane = tid & 63;
    const int wid  = tid >> 6;
    const int b0   = wid * 2;

    // packed per-h constants
    f2 p2[4], q2[4], r2[4], cb2[4], c22[4];
#pragma unroll
    for (int j = 0; j < 4; ++j) {
        p2[j].x  = c1w[(2*j)*3 + 0];  p2[j].y  = c1w[(2*j+1)*3 + 0];
        q2[j].x  = c1w[(2*j)*3 + 1];  q2[j].y  = c1w[(2*j+1)*3 + 1];
        r2[j].x  = c1w[(2*j)*3 + 2];  r2[j].y  = c1w[(2*j+1)*3 + 2];
        cb2[j].x = c1b[2*j];          cb2[j].y = c1b[2*j+1];
        c22[j].x = c2w[2*j];          c22[j].y = c2w[2*j+1];
    }
    const float c2b   = *c2b_p;
    const float scale = RATE / (float)(*bn_p);
    const float S0    = S[b0];
    const float S1    = S[b0 + 1];
    const float vj0   = vjA[(size_t)(b0    ) * O + o];
    const float vj1   = vjA[(size_t)(b0 + 1) * O + o];

    f2 k20[4], k21[4];
#pragma unroll
    for (int j = 0; j < 4; ++j) {
        k20[j] = splat2(vj0) * r2[j] + cb2[j];
        k21[j] = splat2(vj1) * r2[j] + cb2[j];
    }

    const float* __restrict__ wrow = w + (size_t)o * I;
    constexpr int NC = I / 1024;     // chunks of 1024 cols

    f2 acc0 = splat2(0.f), acc1 = splat2(0.f);

    for (int c = 0; c < NC; ++c) {
        if (c) __syncthreads();
        // stage chunk: row s, cols [c*1024, c*1024+1024)
#pragma unroll
        for (int s = 0; s < 8; ++s) {
            *(f4*)&sA[s * 1024 + tid * 4] =
                *(const f4*)(vi + (size_t)s * I + c * 1024 + tid * 4);
        }
        __syncthreads();

        for (int it = 0; it < 4; ++it) {
            const int base = it * 256 + lane * 4;
            const f4 wv4 = *(const f4*)(wrow + c * 1024 + base);
            const f4 a04 = *(const f4*)&sA[b0 * 1024 + base];
            const f4 a14 = *(const f4*)&sA[(b0 + 1) * 1024 + base];
#pragma unroll
            for (int e = 0; e < 4; ++e) {
                const f2 wvE = splat2(wv4[e]);
                const f2 a0E = splat2(a04[e]);
                const f2 a1E = splat2(a14[e]);
                f2 t0 = splat2(0.f), t1 = splat2(0.f);
#pragma unroll
                for (int j = 0; j < 4; ++j) {
                    f2 z0 = wvE * q2[j] + k20[j];
                    z0 = a0E * p2[j] + z0;
                    const f2 u0 = __builtin_elementwise_max(z0, splat2(0.f));
                    t0 = u0 * c22[j] + t0;
                    f2 z1 = wvE * q2[j] + k21[j];
                    z1 = a1E * p2[j] + z1;
                    const f2 u1 = __builtin_elementwise_max(z1, splat2(0.f));
                    t1 = u1 * c22[j] + t1;
                }
                acc0 = a0E * t0 + acc0;
                acc1 = a1E * t1 + acc1;
            }
        }
    }

    float r0 = acc0.x + acc0.y;
    float r1 = acc1.x + acc1.y;
#pragma unroll
    for (int off = 1; off < 64; off <<= 1) {
        r0 += __shfl_xor(r0, off, 64);
        r1 += __shfl_xor(r1, off, 64);
    }
    if (lane == 0) {
        out[(size_t)(b0    ) * O + o] = vj0 + scale * (r0 + c2b * S0);
        out[(size_t)(b0 + 1) * O + o] = vj1 + scale * (r1 + c2b * S1);
    }
}

extern "C" void kernel_launch(void* const* d_in, const int* in_sizes, int n_in,
                              void* d_out, int out_size, void* d_ws, size_t ws_size,
                              hipStream_t stream) {
    const float* x   = (const float*)d_in[0];   // (8, 1024)
    const float* w1  = (const float*)d_in[1];   // (2048, 1024)
    const float* b1  = (const float*)d_in[2];   // (2048,)
    const float* w2  = (const float*)d_in[3];   // (512, 2048)
    const float* b2  = (const float*)d_in[4];   // (512,)
    const float* c1w = (const float*)d_in[5];   // (8, 3)
    const float* c1b = (const float*)d_in[6];   // (8,)
    const float* c2w = (const float*)d_in[7];   // (8,)
    const float* c2b = (const float*)d_in[8];   // ()
    const int*   bn  = (const int*)d_in[9];     // scalar

    float* out = (float*)d_out;                 // (8, 512) fp32
    float* ws  = (float*)d_ws;

    // ws layout (floats): vj1[16384] | S1[16] | out1[16384] | vj2[4096] | S2[16]
    float* vj1  = ws;
    float* S1   = ws + 16384;
    float* out1 = ws + 16400;
    float* vj2  = ws + 32784;
    float* S2   = ws + 36880;

    // layer 1: O=2048, I=1024
    hebb_vj<1024>  <<<2048/4 + 2, 256, 0, stream>>>(x, w1, b1, vj1, S1, 2048, 2048/4);
    hebb_main<1024><<<2048,       256, 0, stream>>>(x, w1, vj1, S1, c1w, c1b, c2w, c2b, bn, out1, 2048);
    // layer 2: O=512, I=2048 (input = out1)
    hebb_vj<2048>  <<<512/4 + 2,  256, 0, stream>>>(out1, w2, b2, vj2, S2, 512, 512/4);
    hebb_main<2048><<<512,        256, 0, stream>>>(out1, w2, vj2, S2, c1w, c1b, c2w, c2b, bn, out, 512);
}

// Round 4
// 100.269 us; speedup vs baseline: 1.1274x; 1.1274x over previous
//
#include <hip/hip_runtime.h>

#define RATE 0.001f

typedef float f2 __attribute__((ext_vector_type(2)));
typedef float f4 __attribute__((ext_vector_type(4)));

static __device__ __forceinline__ f2 splat2(float v) { f2 r; r.x = v; r.y = v; return r; }
static __device__ __forceinline__ f2 vfma2(f2 a, f2 b, f2 c) { return __builtin_elementwise_fma(a, b, c); }

// Fused Hebbian layer, one kernel per layer, no LDS.
// Block = 512 threads = 8 waves; wave w owns batch row b=w; block owns output neuron o.
// out[b,o] = vj + scale*( sum_i a_i*(sum_h relu(a_i*p_h + w_oi*q_h + vj*r_h + c1b_h)*c2w_h)
//                          + c2b * sum_i a_i ),  vj = relu(dot(a_b, w_o) + bias_o)
// All reductions are wave-local butterflies (wave sees only its own b).
// h (8) packed into 4 x f2 -> v_pk_fma_f32 / v_pk_max_f32 on gfx950.
template<int I>
__global__ __launch_bounds__(512) void hebb_layer(
    const float* __restrict__ vi,    // (8, I)
    const float* __restrict__ w,     // (O, I)
    const float* __restrict__ bias,  // (O,)
    const float* __restrict__ c1w,   // (8, 3): p,q,r
    const float* __restrict__ c1b,   // (8,)
    const float* __restrict__ c2w,   // (8,)
    const float* __restrict__ c2b_p, // scalar
    const int*   __restrict__ bn_p,  // scalar batch_num
    float* __restrict__ out,         // (8, O)
    int O)
{
    const int o    = blockIdx.x;
    const int tid  = threadIdx.x;
    const int lane = tid & 63;
    const int b    = tid >> 6;       // wave id == batch row

    const float* __restrict__ wrow = w  + (size_t)o * I;
    const float* __restrict__ arow = vi + (size_t)b * I;

    constexpr int ITERS = I / 256;   // 64 lanes * 4 floats per iter

    // ---- pass 1: dot(a_b, w_o) and rowsum(a_b), wave-local ----
    float dot = 0.f, ss = 0.f;
    for (int it = 0; it < ITERS; ++it) {
        const int base = it * 256 + lane * 4;
        const f4 wv = *(const f4*)(wrow + base);
        const f4 av = *(const f4*)(arow + base);
#pragma unroll
        for (int e = 0; e < 4; ++e) {
            dot = fmaf(av[e], wv[e], dot);
            ss += av[e];
        }
    }
#pragma unroll
    for (int off = 1; off < 64; off <<= 1) {
        dot += __shfl_xor(dot, off, 64);
        ss  += __shfl_xor(ss,  off, 64);
    }
    const float vj = fmaxf(dot + bias[o], 0.f);

    // steady-state constants: p,q,c2 packed pairs; K[h] = vj*r_h + c1b_h
    f2 p2[4], q2[4], c22[4], K2[4];
#pragma unroll
    for (int j = 0; j < 4; ++j) {
        p2[j].x  = c1w[(2*j)*3 + 0];  p2[j].y  = c1w[(2*j+1)*3 + 0];
        q2[j].x  = c1w[(2*j)*3 + 1];  q2[j].y  = c1w[(2*j+1)*3 + 1];
        c22[j].x = c2w[2*j];          c22[j].y = c2w[2*j+1];
        K2[j].x  = fmaf(vj, c1w[(2*j)*3 + 2], c1b[2*j]);
        K2[j].y  = fmaf(vj, c1w[(2*j+1)*3 + 2], c1b[2*j+1]);
    }
    const float c2b   = *c2b_p;
    const float scale = RATE / (float)(*bn_p);

    // ---- pass 2: meta-MLP accumulation (streams are L1/L2-hot from pass 1) ----
    f2 acc = splat2(0.f);
    for (int it = 0; it < ITERS; ++it) {
        const int base = it * 256 + lane * 4;
        const f4 wv4 = *(const f4*)(wrow + base);
        const f4 av4 = *(const f4*)(arow + base);
#pragma unroll
        for (int e = 0; e < 4; ++e) {
            const f2 wvE = splat2(wv4[e]);
            const f2 aE  = splat2(av4[e]);
            f2 t = splat2(0.f);
#pragma unroll
            for (int j = 0; j < 4; ++j) {
                f2 z = vfma2(wvE, q2[j], K2[j]);
                z = vfma2(aE, p2[j], z);
                const f2 u = __builtin_elementwise_max(z, splat2(0.f));
                t = vfma2(u, c22[j], t);
            }
            acc = vfma2(aE, t, acc);
        }
    }
    float r = acc.x + acc.y;
#pragma unroll
    for (int off = 1; off < 64; off <<= 1) r += __shfl_xor(r, off, 64);

    if (lane == 0) out[(size_t)b * O + o] = vj + scale * (r + c2b * ss);
}

extern "C" void kernel_launch(void* const* d_in, const int* in_sizes, int n_in,
                              void* d_out, int out_size, void* d_ws, size_t ws_size,
                              hipStream_t stream) {
    const float* x   = (const float*)d_in[0];   // (8, 1024)
    const float* w1  = (const float*)d_in[1];   // (2048, 1024)
    const float* b1  = (const float*)d_in[2];   // (2048,)
    const float* w2  = (const float*)d_in[3];   // (512, 2048)
    const float* b2  = (const float*)d_in[4];   // (512,)
    const float* c1w = (const float*)d_in[5];   // (8, 3)
    const float* c1b = (const float*)d_in[6];   // (8,)
    const float* c2w = (const float*)d_in[7];   // (8,)
    const float* c2b = (const float*)d_in[8];   // ()
    const int*   bn  = (const int*)d_in[9];     // scalar

    float* out = (float*)d_out;                 // (8, 512) fp32
    float* mid = (float*)d_ws;                  // (8, 2048) fp32 = 64 KB

    hebb_layer<1024><<<2048, 512, 0, stream>>>(x,   w1, b1, c1w, c1b, c2w, c2b, bn, mid, 2048);
    hebb_layer<2048><<<512,  512, 0, stream>>>(mid, w2, b2, c1w, c1b, c2w, c2b, bn, out, 512);
}